// Round 7
// baseline (113.364 us; speedup 1.0000x reference)
//
#include <hip/hip_runtime.h>
#include <math.h>

// AR-GAS Student-t filter, K = 4194304 sequential steps.
// Chunked scan with burn-in (contractive map). R7: redundancy cut to 5x
// (CHUNK 32, BURN 128 -> 160 steps/thread, 320 wave-steps/SIMD vs R6's 832)
// AND the kernel is launched TWICE per kernel_launch: dur_us = overhead +
// 2*K, giving a direct measurement of kernel time K (rocprof top-5 is
// blocked by the harness's 43us poison fills). u = nu*s2 state transform
// (10 VALU/step). 3 barriers. Swizzle +4-per-32 floats: thread stride 36
// dwords == 4 mod 32 -> b128 reads/writes hit all 32 banks evenly (8/bank,
// conflict-free). sigma gets its own LDS region (no reg array, no extra
// barrier pair). 512 blocks x 256 thr, 72.6 KiB LDS -> 2 blocks/CU.

#define CHUNK  32
#define BURN   128
#define BLOCK  256
#define OUTW   (BLOCK * CHUNK)           // 8192 outputs per block
#define REGION (OUTW + BURN)             // 8320 staged y elements
#define SWZ(e) ((e) + 4 * ((e) >> 5))    // +4 floats per 32; keeps 16B align
#define SY_PAD 9360                      // > SWZ(REGION-1) = 9355
#define SZ_PAD 9216                      // > SWZ(OUTW-1)   = 9211

__global__ __launch_bounds__(BLOCK, 2)
void ar_gas_kernel(const float* __restrict__ y,
                   const float* __restrict__ p_last_mu,
                   const float* __restrict__ p_last_s2,
                   const float* __restrict__ p_amu,
                   const float* __restrict__ p_as,
                   const float* __restrict__ p_bmu,
                   const float* __restrict__ p_bs,
                   const float* __restrict__ p_wmu,
                   const float* __restrict__ p_ws,
                   const float* __restrict__ p_nu,
                   const float* __restrict__ p_str,
                   float* __restrict__ out,
                   int n)
{
    __shared__ __align__(16) float sy[SY_PAD];   // staged y; mu written in-place
    __shared__ __align__(16) float sz[SZ_PAD];   // sigma staging
    const int t     = threadIdx.x;
    const int blk   = blockIdx.x;
    const int gbase = blk * OUTW - BURN;         // global index of LDS elem 0

    const float nu       = *p_nu;
    const float strength = *p_str;
    const float a_mu = (*p_amu) * strength;
    const float a_s  = (*p_as)  * strength;
    const float b_mu = *p_bmu;
    const float b_s  = *p_bs;
    const float w_mu = *p_wmu;
    const float w_s  = *p_ws;

    // u = nu*s2 transform (algebraically == reference):
    //   r=y-mu; den=u+r^2; t2=u*r/den
    //   mu' = w_mu + b_mu*mu + (b_mu*a_mu*k1)*t2,   k1=(nu+1)/nu
    //   u'  = nu*w_s + b_s*(1-a_s)*u + (nu*b_s*a_s*k1)*(t2*r);  sigma=sqrt(u/nu)
    const float inv_nu = __builtin_amdgcn_rcpf(nu);
    const float k1   = (nu + 1.0f) * inv_nu;
    const float bamk = b_mu * a_mu * k1;
    const float bask = nu * b_s * a_s * k1;
    const float c3   = b_s * (1.0f - a_s);
    const float wsn  = nu * w_s;

    // ---- stage y region: coalesced float4 global loads -> swizzled LDS ----
    #pragma unroll
    for (int it = 0; it < 9; ++it) {
        int idx = (t + BLOCK * it) * 4;          // idx%32 in {0,4,...,28}
        if (idx < REGION) {
            int g = gbase + idx;
            float4 v = make_float4(0.f, 0.f, 0.f, 0.f);
            if (g >= 0) v = *(const float4*)(y + g);   // block-0 pre-pad = 0
            *(float4*)(sy + SWZ(idx)) = v;
        }
    }
    __syncthreads();

    // ---- initial state ----
    // thread t: burn elems [32t, 32t+128), emit elems [32t+128, 32t+160)
    // block 0, t<=4: burn-start global = 32t-128 <= 0 -> exact seed; the
    // first (4-t) runs step over zero-pad and are undone by predicated hold.
    int skipR = 0;
    float mu, u;
    if (blk == 0 && t <= 4) {
        mu    = *p_last_mu;
        u     = nu * (*p_last_s2);   // "last_sigma" is the variance
        skipR = 4 - t;
    } else {                         // stationary guess; 128-step burn erases it
        mu = w_mu * __builtin_amdgcn_rcpf(fmaxf(1.0f - b_mu, 1e-12f));
        u  = wsn  * __builtin_amdgcn_rcpf(fmaxf(1.0f - b_s,  1e-12f));
    }
    const float muS = mu, uS = u;    // seed copy for predicated hold

#define STEP(yv) do {                                   \
        float r   = (yv) - mu;                          \
        float den = fmaf(r, r, u);                      \
        float inv = __builtin_amdgcn_rcpf(den);         \
        float t2  = (u * r) * inv;                      \
        mu = fmaf(bamk, t2, fmaf(b_mu, mu, w_mu));      \
        u  = fmaf(bask, t2 * r, fmaf(c3, u, wsn));      \
    } while (0)
#define LDRUN(B, off) do { _Pragma("unroll")                         \
        for (int k = 0; k < 8; ++k)                                  \
            B[k] = *(const float4*)(sy + (off) + 4 * k); } while (0)
#define RUN32(B) do { _Pragma("unroll")                              \
        for (int k = 0; k < 8; ++k) {                                \
            STEP(B[k].x); STEP(B[k].y); STEP(B[k].z); STEP(B[k].w);  \
        } } while (0)

    // ---- burn-in: 4 runs of 32 steps, ping-pong run-level prefetch ----
    const int b0 = 36 * t;           // padded base: SWZ(32t); run r at b0+36r
    float4 P[8], Q[8];
    LDRUN(P, b0);
    LDRUN(Q, b0 + 36);
    RUN32(P);  if (0 < skipR) { mu = muS; u = uS; }
    LDRUN(P, b0 + 72);
    RUN32(Q);  if (1 < skipR) { mu = muS; u = uS; }
    LDRUN(Q, b0 + 108);
    RUN32(P);  if (2 < skipR) { mu = muS; u = uS; }
    LDRUN(P, b0 + 144);              // emit-run data: own slots, safe pre-barrier
    RUN32(Q);  if (3 < skipR) { mu = muS; u = uS; }

    // all cross-thread burn reads must complete before in-place mu writes:
    __syncthreads();

    // ---- emit: 32 steps; mu in-place over consumed y; sigma -> sz ----
    {
        const int pe = b0 + 144;     // SWZ(32t+128)
        const int ze = b0;           // SWZ(32t) in sz
        float4 m, s;
        #pragma unroll
        for (int q = 0; q < 8; ++q) {
            STEP(P[q].x); m.x = mu; s.x = __builtin_amdgcn_sqrtf(u * inv_nu);
            STEP(P[q].y); m.y = mu; s.y = __builtin_amdgcn_sqrtf(u * inv_nu);
            STEP(P[q].z); m.z = mu; s.z = __builtin_amdgcn_sqrtf(u * inv_nu);
            STEP(P[q].w); m.w = mu; s.w = __builtin_amdgcn_sqrtf(u * inv_nu);
            *(float4*)(sy + pe + 4 * q) = m;
            *(float4*)(sz + ze + 4 * q) = s;
        }
    }
#undef RUN32
#undef LDRUN
#undef STEP
    __syncthreads();

    // ---- coalesced float4 copy-out of both outputs ----
    const int obase = blk * OUTW;
    #pragma unroll
    for (int it = 0; it < 8; ++it) {
        int idx = (t + BLOCK * it) * 4;
        int f   = SWZ(idx + BURN);               // 4 contiguous padded slots
        int fz  = SWZ(idx);
        *(float4*)(out + obase + idx) =
            make_float4(sy[f], sy[f + 1], sy[f + 2], sy[f + 3]);
        *(float4*)(out + n + obase + idx) =
            make_float4(sz[fz], sz[fz + 1], sz[fz + 2], sz[fz + 3]);
    }
}

extern "C" void kernel_launch(void* const* d_in, const int* in_sizes, int n_in,
                              void* d_out, int out_size, void* d_ws, size_t ws_size,
                              hipStream_t stream) {
    const float* y = (const float*)d_in[0];
    const int n    = in_sizes[0];              // 4194304 = 512 * 8192
    const int grid = n / OUTW;                 // 512 blocks

    // Launched TWICE (identical, idempotent): dur_us = overhead + 2*K,
    // measuring kernel time K directly since rocprof top-5 is fill-blocked.
    for (int rep = 0; rep < 2; ++rep) {
        ar_gas_kernel<<<grid, BLOCK, 0, stream>>>(
            y,
            (const float*)d_in[1],  // last_mu
            (const float*)d_in[2],  // last_sigma (variance)
            (const float*)d_in[3],  // alpha_mu
            (const float*)d_in[4],  // alpha_sigma
            (const float*)d_in[5],  // beta_mu
            (const float*)d_in[6],  // beta_sigma
            (const float*)d_in[7],  // omega_mu
            (const float*)d_in[8],  // omega_sigma
            (const float*)d_in[9],  // nu
            (const float*)d_in[10], // norm_strength
            (float*)d_out, n);
    }
}

// Round 8
// 97.419 us; speedup vs baseline: 1.1637x; 1.1637x over previous
//
#include <hip/hip_runtime.h>
#include <math.h>

// AR-GAS Student-t filter, K = 4194304 sequential steps.
// Chunked scan with burn-in (contractive map, mean per-step factor ~0.93).
// R8: single launch (R7's 2x was a diagnostic: K ~= 22.7us, F ~= 10us fixed,
// ~37 cy/wave-step). Redundancy 5x -> 4x: CHUNK 32, BURN 96 -> 128
// steps/thread, 256 wave-steps/SIMD. Burn residual ~3e-4 << bf16-ULP floor.
// u = nu*s2 transform (10 VALU/step). Swizzle +4-per-32: b128 reads at
// thread stride 36 dwords (== 4 mod 32) hit all 32 banks evenly. Ping-pong
// run-level prefetch. 512 blocks x 256 thr, ~72 KiB LDS -> 2 blocks/CU.

#define CHUNK  32
#define BURN   96
#define NRUN   (BURN / 32)               // 3 burn runs
#define BLOCK  256
#define OUTW   (BLOCK * CHUNK)           // 8192 outputs per block
#define REGION (OUTW + BURN)             // 8288 staged y elements
#define SWZ(e) ((e) + 4 * ((e) >> 5))    // +4 floats per 32; keeps 16B align
#define SY_PAD 9320                      // > SWZ(REGION-1) = 9319
#define SZ_PAD 9216                      // > SWZ(OUTW-1)   = 9211

__global__ __launch_bounds__(BLOCK, 2)
void ar_gas_kernel(const float* __restrict__ y,
                   const float* __restrict__ p_last_mu,
                   const float* __restrict__ p_last_s2,
                   const float* __restrict__ p_amu,
                   const float* __restrict__ p_as,
                   const float* __restrict__ p_bmu,
                   const float* __restrict__ p_bs,
                   const float* __restrict__ p_wmu,
                   const float* __restrict__ p_ws,
                   const float* __restrict__ p_nu,
                   const float* __restrict__ p_str,
                   float* __restrict__ out,
                   int n)
{
    __shared__ __align__(16) float sy[SY_PAD];   // staged y; mu written in-place
    __shared__ __align__(16) float sz[SZ_PAD];   // sigma staging
    const int t     = threadIdx.x;
    const int blk   = blockIdx.x;
    const int gbase = blk * OUTW - BURN;         // global index of LDS elem 0

    const float nu       = *p_nu;
    const float strength = *p_str;
    const float a_mu = (*p_amu) * strength;
    const float a_s  = (*p_as)  * strength;
    const float b_mu = *p_bmu;
    const float b_s  = *p_bs;
    const float w_mu = *p_wmu;
    const float w_s  = *p_ws;

    // u = nu*s2 transform (algebraically == reference):
    //   r=y-mu; den=u+r^2; t2=u*r/den
    //   mu' = w_mu + b_mu*mu + (b_mu*a_mu*k1)*t2,   k1=(nu+1)/nu
    //   u'  = nu*w_s + b_s*(1-a_s)*u + (nu*b_s*a_s*k1)*(t2*r); sigma=sqrt(u/nu)
    const float inv_nu = __builtin_amdgcn_rcpf(nu);
    const float k1   = (nu + 1.0f) * inv_nu;
    const float bamk = b_mu * a_mu * k1;
    const float bask = nu * b_s * a_s * k1;
    const float c3   = b_s * (1.0f - a_s);
    const float wsn  = nu * w_s;

    // ---- stage y region: coalesced float4 global loads -> swizzled LDS ----
    #pragma unroll
    for (int it = 0; it < 9; ++it) {
        int idx = (t + BLOCK * it) * 4;          // idx%32 in {0,4,...,28}
        if (idx < REGION) {
            int g = gbase + idx;
            float4 v = make_float4(0.f, 0.f, 0.f, 0.f);
            if (g >= 0) v = *(const float4*)(y + g);   // block-0 pre-pad = 0
            *(float4*)(sy + SWZ(idx)) = v;
        }
    }
    __syncthreads();

    // ---- initial state ----
    // thread t: burn elems [32t, 32t+96), emit elems [32t+96, 32t+128).
    // block 0: burn-start global = 32t-96 <= 0 for t<=3 -> exact seed; the
    // first (3-t) runs step over zero-pad and are undone by predicated hold.
    int skipR = 0;
    float mu, u;
    if (blk == 0 && t <= NRUN) {
        mu    = *p_last_mu;
        u     = nu * (*p_last_s2);   // "last_sigma" is the variance
        skipR = NRUN - t;
    } else {                         // stationary guess; 96-step burn erases it
        mu = w_mu * __builtin_amdgcn_rcpf(fmaxf(1.0f - b_mu, 1e-12f));
        u  = wsn  * __builtin_amdgcn_rcpf(fmaxf(1.0f - b_s,  1e-12f));
    }
    const float muS = mu, uS = u;    // seed copy for predicated hold

#define STEP(yv) do {                                   \
        float r   = (yv) - mu;                          \
        float den = fmaf(r, r, u);                      \
        float inv = __builtin_amdgcn_rcpf(den);         \
        float t2  = (u * r) * inv;                      \
        mu = fmaf(bamk, t2, fmaf(b_mu, mu, w_mu));      \
        u  = fmaf(bask, t2 * r, fmaf(c3, u, wsn));      \
    } while (0)
#define LDRUN(B, off) do { _Pragma("unroll")                         \
        for (int k = 0; k < 8; ++k)                                  \
            B[k] = *(const float4*)(sy + (off) + 4 * k); } while (0)
#define RUN32(B) do { _Pragma("unroll")                              \
        for (int k = 0; k < 8; ++k) {                                \
            STEP(B[k].x); STEP(B[k].y); STEP(B[k].z); STEP(B[k].w);  \
        } } while (0)

    // ---- burn-in: 3 runs of 32 steps, ping-pong run-level prefetch ----
    const int b0 = 36 * t;           // padded base: SWZ(32t); run r at b0+36r
    float4 P[8], Q[8];
    LDRUN(P, b0);
    LDRUN(Q, b0 + 36);
    RUN32(P);  if (0 < skipR) { mu = muS; u = uS; }
    LDRUN(P, b0 + 72);
    RUN32(Q);  if (1 < skipR) { mu = muS; u = uS; }
    LDRUN(Q, b0 + 108);              // emit-run data: own slots, safe pre-barrier
    RUN32(P);  if (2 < skipR) { mu = muS; u = uS; }

    // all cross-thread burn reads must complete before in-place mu writes:
    __syncthreads();

    // ---- emit: 32 steps; mu in-place over consumed y; sigma -> sz ----
    {
        const int pe = b0 + 108;     // SWZ(32t+96)
        const int ze = b0;           // SWZ(32t) in sz
        float4 m, s;
        #pragma unroll
        for (int q = 0; q < 8; ++q) {
            STEP(Q[q].x); m.x = mu; s.x = __builtin_amdgcn_sqrtf(u * inv_nu);
            STEP(Q[q].y); m.y = mu; s.y = __builtin_amdgcn_sqrtf(u * inv_nu);
            STEP(Q[q].z); m.z = mu; s.z = __builtin_amdgcn_sqrtf(u * inv_nu);
            STEP(Q[q].w); m.w = mu; s.w = __builtin_amdgcn_sqrtf(u * inv_nu);
            *(float4*)(sy + pe + 4 * q) = m;
            *(float4*)(sz + ze + 4 * q) = s;
        }
    }
#undef RUN32
#undef LDRUN
#undef STEP
    __syncthreads();

    // ---- coalesced float4 copy-out of both outputs ----
    const int obase = blk * OUTW;
    #pragma unroll
    for (int it = 0; it < 8; ++it) {
        int idx = (t + BLOCK * it) * 4;
        int f   = SWZ(idx) + 108;                // SWZ(idx + 96), 4 contiguous
        int fz  = SWZ(idx);
        *(float4*)(out + obase + idx) =
            make_float4(sy[f], sy[f + 1], sy[f + 2], sy[f + 3]);
        *(float4*)(out + n + obase + idx) =
            make_float4(sz[fz], sz[fz + 1], sz[fz + 2], sz[fz + 3]);
    }
}

extern "C" void kernel_launch(void* const* d_in, const int* in_sizes, int n_in,
                              void* d_out, int out_size, void* d_ws, size_t ws_size,
                              hipStream_t stream) {
    const float* y = (const float*)d_in[0];
    const int n    = in_sizes[0];              // 4194304 = 512 * 8192
    const int grid = n / OUTW;                 // 512 blocks

    ar_gas_kernel<<<grid, BLOCK, 0, stream>>>(
        y,
        (const float*)d_in[1],  // last_mu
        (const float*)d_in[2],  // last_sigma (variance)
        (const float*)d_in[3],  // alpha_mu
        (const float*)d_in[4],  // alpha_sigma
        (const float*)d_in[5],  // beta_mu
        (const float*)d_in[6],  // beta_sigma
        (const float*)d_in[7],  // omega_mu
        (const float*)d_in[8],  // omega_sigma
        (const float*)d_in[9],  // nu
        (const float*)d_in[10], // norm_strength
        (float*)d_out, n);
}